// Round 1
// baseline (5440.702 us; speedup 1.0000x reference)
//
#include <hip/hip_runtime.h>
#include <hip/hip_bf16.h>

#define H 128
#define FOURH 512
#define BATCH 64
#define SEQ 2048

// ---------------- prep: transpose Wih -> [K][512], sum biases ----------------
__global__ void prep_kernel(const float* __restrict__ Wih0, const float* __restrict__ Wih1,
                            const float* __restrict__ bih0, const float* __restrict__ bhh0,
                            const float* __restrict__ bih1, const float* __restrict__ bhh1,
                            float* __restrict__ Wt0, float* __restrict__ Wt1,
                            float* __restrict__ b0, float* __restrict__ b1) {
    int id = blockIdx.x * 256 + threadIdx.x;
    const int N0 = 256 * 512;      // Wt0 elements
    const int N1 = 128 * 512;      // Wt1 elements
    if (id < N0) {
        int k = id >> 9, n = id & 511;
        Wt0[id] = Wih0[n * 256 + k];
    } else if (id < N0 + N1) {
        int i = id - N0;
        int k = i >> 9, n = i & 511;
        Wt1[i] = Wih1[n * 128 + k];
    } else if (id < N0 + N1 + 512) {
        int i = id - (N0 + N1);
        b0[i] = bih0[i] + bhh0[i];
    } else if (id < N0 + N1 + 1024) {
        int i = id - (N0 + N1 + 512);
        b1[i] = bih1[i] + bhh1[i];
    }
}

// ---------------- fp32 GEMM: G[m][n] = sum_k A[row(m)][k]*Bt[k][n] + bias[n] --
// A rows are mapped: m (chunk row) -> b = m>>tcShift, tl = m & (Tc-1),
// global row = b*rowsPerBatch + t0 + tl.
#define BM 128
#define BN 128
#define BK 32

__global__ __launch_bounds__(256) void gemm_bias_kernel(
    const float* __restrict__ A, int lda, int rowsPerBatch, int t0,
    const float* __restrict__ Bt, const float* __restrict__ bias,
    float* __restrict__ G, int K, int tcShift)
{
    __shared__ float As[BK][BM + 4];   // +4 pad keeps 16B alignment, breaks write conflicts
    __shared__ float Bs[BK][BN];

    const int tid = threadIdx.x;
    const int m0 = blockIdx.y * BM;
    const int n0 = blockIdx.x * BN;
    const int tm = tid >> 4;   // 0..15
    const int tn = tid & 15;   // 0..15
    const int tcMask = (1 << tcShift) - 1;

    // A-load assignments: 1024 float4s, 4 per thread. row = fidx>>3, q = fidx&7
    const float* aptr[4];
    int ar[4], aq[4];
#pragma unroll
    for (int l = 0; l < 4; ++l) {
        int fidx = tid + l * 256;
        int r = fidx >> 3, q = fidx & 7;
        ar[l] = r; aq[l] = q;
        int m = m0 + r;
        int bi = m >> tcShift;
        int tl = m & tcMask;
        aptr[l] = A + ((size_t)bi * rowsPerBatch + t0 + tl) * lda + q * 4;
    }
    // B-load assignments: kk = fidx>>5, q = fidx&31
    int bkk[4], bq[4];
#pragma unroll
    for (int l = 0; l < 4; ++l) {
        int fidx = tid + l * 256;
        bkk[l] = fidx >> 5; bq[l] = fidx & 31;
    }

    float acc[2][2][4][4];
#pragma unroll
    for (int ri = 0; ri < 2; ++ri)
#pragma unroll
        for (int ci = 0; ci < 2; ++ci)
#pragma unroll
            for (int i = 0; i < 4; ++i)
#pragma unroll
                for (int j = 0; j < 4; ++j) acc[ri][ci][i][j] = 0.f;

    for (int k0 = 0; k0 < K; k0 += BK) {
        __syncthreads();
#pragma unroll
        for (int l = 0; l < 4; ++l) {
            float4 v = *(const float4*)(aptr[l] + k0);
            As[aq[l] * 4 + 0][ar[l]] = v.x;
            As[aq[l] * 4 + 1][ar[l]] = v.y;
            As[aq[l] * 4 + 2][ar[l]] = v.z;
            As[aq[l] * 4 + 3][ar[l]] = v.w;
        }
#pragma unroll
        for (int l = 0; l < 4; ++l) {
            float4 v = *(const float4*)(Bt + (size_t)(k0 + bkk[l]) * FOURH + n0 + bq[l] * 4);
            *(float4*)&Bs[bkk[l]][bq[l] * 4] = v;
        }
        __syncthreads();
#pragma unroll
        for (int kk = 0; kk < BK; ++kk) {
            float a[8], bb[8];
            *(float4*)&a[0] = *(const float4*)&As[kk][tm * 4];
            *(float4*)&a[4] = *(const float4*)&As[kk][64 + tm * 4];
            *(float4*)&bb[0] = *(const float4*)&Bs[kk][tn * 4];
            *(float4*)&bb[4] = *(const float4*)&Bs[kk][64 + tn * 4];
#pragma unroll
            for (int ri = 0; ri < 2; ++ri)
#pragma unroll
                for (int i = 0; i < 4; ++i)
#pragma unroll
                    for (int ci = 0; ci < 2; ++ci)
#pragma unroll
                        for (int j = 0; j < 4; ++j)
                            acc[ri][ci][i][j] = fmaf(a[ri * 4 + i], bb[ci * 4 + j], acc[ri][ci][i][j]);
        }
    }

    float4 bv0 = *(const float4*)&bias[n0 + tn * 4];
    float4 bv1 = *(const float4*)&bias[n0 + 64 + tn * 4];
#pragma unroll
    for (int ri = 0; ri < 2; ++ri)
#pragma unroll
        for (int i = 0; i < 4; ++i) {
            int m = m0 + ri * 64 + tm * 4 + i;
            float* gp = G + (size_t)m * FOURH + n0;
            float4 o0 = make_float4(acc[ri][0][i][0] + bv0.x, acc[ri][0][i][1] + bv0.y,
                                    acc[ri][0][i][2] + bv0.z, acc[ri][0][i][3] + bv0.w);
            float4 o1 = make_float4(acc[ri][1][i][0] + bv1.x, acc[ri][1][i][1] + bv1.y,
                                    acc[ri][1][i][2] + bv1.z, acc[ri][1][i][3] + bv1.w);
            *(float4*)(gp + tn * 4) = o0;
            *(float4*)(gp + 64 + tn * 4) = o1;
        }
}

// ---------------- LSTM scan ----------------
__device__ __forceinline__ float sigmoid_f(float x) {
    return __builtin_amdgcn_rcpf(1.f + __expf(-x));
}
__device__ __forceinline__ float tanh_f(float x) {
    // 1 - 2/(e^{2x}+1); saturates correctly at +-inf
    return 1.f - 2.f * __builtin_amdgcn_rcpf(__expf(2.f * x) + 1.f);
}
#define RL(v, k) __int_as_float(__builtin_amdgcn_readlane(__float_as_int(v), (k)))

// 64 blocks (one per batch), 512 threads (thread t owns gate t; Whh row t in VGPRs).
__global__ __launch_bounds__(512, 2) void lstm_scan_kernel(
    const float* __restrict__ G,      // [B][Tc][512] chunk gate pre-activations (xw + biases)
    const float* __restrict__ Whh,    // [512][128]
    float* __restrict__ Hout,         // output hidden seq
    float* __restrict__ hState, float* __restrict__ cState, // [B][128]
    int Tc, int outBatchStride, int outT0, int firstChunk)
{
    const int b = blockIdx.x;
    const int t = threadIdx.x;      // 0..511
    const int lane = t & 63;

    __shared__ float h_lds[H];
    __shared__ float gate_lds[FOURH];

    // Whh row t -> registers (128 VGPRs)
    float w[H];
    {
        const float4* wr = (const float4*)(Whh + (size_t)t * H);
#pragma unroll
        for (int q = 0; q < H / 4; ++q) {
            float4 v = wr[q];
            w[q * 4 + 0] = v.x; w[q * 4 + 1] = v.y; w[q * 4 + 2] = v.z; w[q * 4 + 3] = v.w;
        }
    }

    float c_reg = 0.f;
    if (t < H) {
        if (firstChunk) {
            h_lds[t] = 0.f;
        } else {
            h_lds[t] = hState[b * H + t];
            c_reg = cState[b * H + t];
        }
    }
    __syncthreads();

    const float* gpc = G + (size_t)b * Tc * FOURH + t;
    float* op = Hout + ((size_t)b * outBatchStride + outT0) * H;
    const bool isG = (t >= 2 * H && t < 3 * H);   // wave-uniform (waves 4,5)

    for (int step = 0; step < Tc; ++step) {
        float h0 = h_lds[lane];
        float h1v = h_lds[64 + lane];
        float gval = *gpc;            // coalesced; consumed ~260 instrs later
        gpc += FOURH;

        float a0 = 0.f, a1 = 0.f, a2 = 0.f, a3 = 0.f;
#pragma unroll
        for (int k = 0; k < 64; k += 4) {
            a0 = fmaf(RL(h0, k + 0), w[k + 0], a0);
            a1 = fmaf(RL(h0, k + 1), w[k + 1], a1);
            a2 = fmaf(RL(h0, k + 2), w[k + 2], a2);
            a3 = fmaf(RL(h0, k + 3), w[k + 3], a3);
        }
#pragma unroll
        for (int k = 0; k < 64; k += 4) {
            a0 = fmaf(RL(h1v, k + 0), w[64 + k + 0], a0);
            a1 = fmaf(RL(h1v, k + 1), w[64 + k + 1], a1);
            a2 = fmaf(RL(h1v, k + 2), w[64 + k + 2], a2);
            a3 = fmaf(RL(h1v, k + 3), w[64 + k + 3], a3);
        }
        float pre = ((a0 + a1) + (a2 + a3)) + gval;
        gate_lds[t] = isG ? tanh_f(pre) : sigmoid_f(pre);
        __syncthreads();

        if (t < H) {
            float ig = gate_lds[t];
            float fg = gate_lds[H + t];
            float gg = gate_lds[2 * H + t];
            float og = gate_lds[3 * H + t];
            float c = fmaf(fg, c_reg, ig * gg);
            c_reg = c;
            float h = og * tanh_f(c);
            h_lds[t] = h;
            op[(size_t)step * H + t] = h;
        }
        __syncthreads();
    }

    if (t < H) {
        hState[b * H + t] = h_lds[t];
        cState[b * H + t] = c_reg;
    }
}

// ---------------- launch ----------------
extern "C" void kernel_launch(void* const* d_in, const int* in_sizes, int n_in,
                              void* d_out, int out_size, void* d_ws, size_t ws_size,
                              hipStream_t stream) {
    const float* x    = (const float*)d_in[0];   // [64,2048,256]
    const float* Wih0 = (const float*)d_in[1];   // [512,256]
    const float* Whh0 = (const float*)d_in[2];   // [512,128]
    const float* bih0 = (const float*)d_in[3];
    const float* bhh0 = (const float*)d_in[4];
    const float* Wih1 = (const float*)d_in[5];   // [512,128]
    const float* Whh1 = (const float*)d_in[6];   // [512,128]
    const float* bih1 = (const float*)d_in[7];
    const float* bhh1 = (const float*)d_in[8];
    float* out = (float*)d_out;                  // [64,2048,128] fp32

    char* ws = (char*)d_ws;
    size_t off = 0;
    auto carve = [&](size_t bytes) -> char* {
        char* p = ws + off;
        off += (bytes + 255) & ~(size_t)255;
        return p;
    };

    float* Wt0 = (float*)carve(256 * 512 * 4);
    float* Wt1 = (float*)carve(128 * 512 * 4);
    float* b0  = (float*)carve(512 * 4);
    float* b1  = (float*)carve(512 * 4);
    float* h0s = (float*)carve(BATCH * H * 4);
    float* c0s = (float*)carve(BATCH * H * 4);
    float* h1s = (float*)carve(BATCH * H * 4);
    float* c1s = (float*)carve(BATCH * H * 4);

    // choose largest power-of-2 chunk that fits the workspace
    int Tc = 2048;
    for (;;) {
        size_t need = off + (size_t)BATCH * Tc * FOURH * 4 + (size_t)BATCH * Tc * H * 4 + 4096;
        if (need <= ws_size || Tc == 128) break;
        Tc >>= 1;
    }
    float* gbuf  = (float*)carve((size_t)BATCH * Tc * FOURH * 4);
    float* h1buf = (float*)carve((size_t)BATCH * Tc * H * 4);
    int tcShift = 31 - __builtin_clz((unsigned)Tc);

    prep_kernel<<<772, 256, 0, stream>>>(Wih0, Wih1, bih0, bhh0, bih1, bhh1, Wt0, Wt1, b0, b1);

    const int nChunks = SEQ / Tc;
    dim3 ggrid(FOURH / BN, (BATCH * Tc) / BM);
    for (int c = 0; c < nChunks; ++c) {
        int t0 = c * Tc;
        // layer 0 input GEMM for this chunk
        gemm_bias_kernel<<<ggrid, 256, 0, stream>>>(x, 256, SEQ, t0, Wt0, b0, gbuf, 256, tcShift);
        // layer 0 scan -> h1buf [B][Tc][H]
        lstm_scan_kernel<<<BATCH, 512, 0, stream>>>(gbuf, Whh0, h1buf, h0s, c0s,
                                                    Tc, Tc, 0, c == 0 ? 1 : 0);
        // layer 1 input GEMM
        gemm_bias_kernel<<<ggrid, 256, 0, stream>>>(h1buf, 128, Tc, 0, Wt1, b1, gbuf, 128, tcShift);
        // layer 1 scan -> d_out [B][2048][H]
        lstm_scan_kernel<<<BATCH, 512, 0, stream>>>(gbuf, Whh1, out, h1s, c1s,
                                                    Tc, SEQ, t0, c == 0 ? 1 : 0);
    }
}